// Round 12
// baseline (88.995 us; speedup 1.0000x reference)
//
#include <hip/hip_runtime.h>
#include <hip/hip_bf16.h>

#define NTOKENS 500000
#define NSAMPLED 8192
#define NHID 256
#define BATCH 8192
#define LROW 8193  // 1 + NSAMPLED
#define OUT_TAIL ((size_t)BATCH * LROW)

typedef short s16x8 __attribute__((ext_vector_type(8)));
typedef float f32x4 __attribute__((ext_vector_type(4)));
typedef unsigned short u16;

// RNE float->bf16
static __device__ __forceinline__ u16 f2bf(float f) {
  unsigned u = __float_as_uint(f);
  return (u16)((u + 0x7fffu + ((u >> 16) & 1u)) >> 16);
}

static __device__ __forceinline__ s16x8 pack8(float4 v0, float4 v1) {
  s16x8 o;
  o[0] = (short)f2bf(v0.x); o[1] = (short)f2bf(v0.y);
  o[2] = (short)f2bf(v0.z); o[3] = (short)f2bf(v0.w);
  o[4] = (short)f2bf(v1.x); o[5] = (short)f2bf(v1.y);
  o[6] = (short)f2bf(v1.z); o[7] = (short)f2bf(v1.w);
  return o;
}

static __device__ __forceinline__ void gload_lds16(const void* g, void* l) {
  __builtin_amdgcn_global_load_lds(
      (const __attribute__((address_space(1))) void*)g,
      (__attribute__((address_space(3))) void*)l, 16, 0, 0);
}

// ---- fused prep: [0,1024) A->bf16 | [1024,2048) gather B->bf16 + colconst
//                  | [2048,4096) true logits + zero targets ----
__global__ void k_prep(const float* __restrict__ inputs, const int* __restrict__ labels,
                       const int* __restrict__ sample_ids, const float* __restrict__ tfreq,
                       const float* __restrict__ sfreq, const float* __restrict__ weight,
                       const float* __restrict__ bias, u16* __restrict__ outA,
                       u16* __restrict__ outB, float* __restrict__ colconst,
                       float* __restrict__ out) {
  int bid = blockIdx.x;
  int t = threadIdx.x;
  if (bid < 1024) {                       // inputs fp32 -> bf16 [BATCH][NHID]
    size_t idx = ((size_t)bid * 256 + t) * 8;
    const float4* p = (const float4*)(inputs + idx);
    *(s16x8*)(outA + idx) = pack8(p[0], p[1]);
  } else if (bid < 2048) {                // gather weight[sample_ids] -> bf16; colconst
    int r = (bid - 1024) * 8 + (t >> 5);
    int l = t & 31;
    int s = sample_ids[r];
    const float* src = weight + (size_t)s * NHID + l * 8;
    *(s16x8*)(outB + (size_t)r * NHID + l * 8) =
        pack8(((const float4*)src)[0], ((const float4*)src)[1]);
    if (l == 0) colconst[r] = bias[s] - sfreq[r];
  } else {                                // true logits (col 0) + int32 zeros tail
    int bb = bid - 2048;
    int w = t >> 6, lane = t & 63;
    int b = bb * 4 + w;
    int lab = labels[b];
    const float4 x = *(const float4*)(inputs + (size_t)b * NHID + lane * 4);
    const float4 ww = *(const float4*)(weight + (size_t)lab * NHID + lane * 4);
    float s = x.x * ww.x + x.y * ww.y + x.z * ww.z + x.w * ww.w;
    #pragma unroll
    for (int off = 32; off; off >>= 1) s += __shfl_down(s, off, 64);
    if (lane == 0) out[(size_t)b * LROW] = s + bias[lab] - tfreq[b];
    int tid = bb * 256 + t;
    if (tid < BATCH) out[OUT_TAIL + tid] = 0.0f;
  }
}

// ---- GEMM: C[b][s] = sum_k A[b][k]*B[s][k] + colconst[s] ----
// 128x256 tile, 8 waves of 32x128. 2-phase DOUBLE-BUFFERED K-loop (T3
// minimum recipe): BK=32 x8 steps; each kt issues next-tile global_load_lds
// BEFORE ds_read+MFMA of current tile, ONE barrier per kt (its vmcnt(0)
// drain waits on loads that had the whole compute phase in flight).
// r11 NaN fix: granule stride is 64 u16 (8 chunks x 8 u16), reads were
// rp*128 (2x, out of bounds). Now rp*64 + slot*8 on both lA and lB.
// LDS 48KB dbuf keeps 2 blocks/CU. Row-pair granules:
// slot = ((row&1)*4+g)^(rp&7) -> same bank structure as r5 (proven).
__global__ __launch_bounds__(512, 4) void k_gemm(const u16* __restrict__ A,
                                                 const u16* __restrict__ B,
                                                 const float* __restrict__ colconst,
                                                 float* __restrict__ out) {
  __shared__ u16 lA[2][128 * 32];  // 8KB per buffer
  __shared__ u16 lB[2][256 * 32];  // 16KB per buffer
  int t = threadIdx.x;
  int lane = t & 63;
  int w = t >> 6;               // 0..7
  int bid = blockIdx.x;
  int brow = bid >> 5;          // 0..63 (128-row tiles), row-major mapping
  int bcol = bid & 31;          // 0..31 (256-col tiles)
  int wr = w >> 1, wc = w & 1;  // wave: rows wr*32+, cols wc*128+
  const int l15 = lane & 15;
  const int lhi = lane >> 4;

  f32x4 acc[2][8];
  #pragma unroll
  for (int a = 0; a < 2; ++a)
    #pragma unroll
    for (int b = 0; b < 8; ++b) acc[a][b] = (f32x4){0.f, 0.f, 0.f, 0.f};

  const u16* Abase = A + (size_t)brow * 128 * NHID;
  const u16* Bbase = B + (size_t)bcol * 256 * NHID;

  // stage one BK=32 K-slice into buffer `buf`: A 512 chunks (1/thr),
  // B 1024 chunks (2/thr). LDS chunk idx holds global (rp=idx>>3,
  // cp=(idx&7)^(rp&7)) -> row = rp*2 + (cp>>2), k-chunk c = cp&3.
  auto stage = [&](int buf, int kt) {
    {
      int idx = w * 64 + lane;
      int rp = idx >> 3, cp = (idx & 7) ^ (rp & 7);
      int row = rp * 2 + (cp >> 2), c = cp & 3;
      gload_lds16(Abase + (size_t)row * NHID + kt * 32 + c * 8,
                  &lA[buf][(size_t)(w * 64) * 8]);
    }
    #pragma unroll
    for (int j = 0; j < 2; ++j) {
      int idx = (w * 2 + j) * 64 + lane;
      int rp = idx >> 3, cp = (idx & 7) ^ (rp & 7);
      int row = rp * 2 + (cp >> 2), c = cp & 3;
      gload_lds16(Bbase + (size_t)row * NHID + kt * 32 + c * 8,
                  &lB[buf][(size_t)((w * 2 + j) * 64) * 8]);
    }
  };

  stage(0, 0);
  __syncthreads();
  int cur = 0;
  for (int kt = 0; kt < 8; ++kt) {
    if (kt < 7) stage(cur ^ 1, kt + 1);  // prefetch next K-slice (fire+forget)
    // ds_read current buffer + MFMA (k-chunk g = lhi within the 32-K slice)
    s16x8 af[2];
    #pragma unroll
    for (int mi = 0; mi < 2; ++mi) {
      int ra = wr * 32 + mi * 16 + l15;
      int rp = ra >> 1;
      int slot = (((ra & 1) << 2) | lhi) ^ (rp & 7);
      af[mi] = *(const s16x8*)(&lA[cur][rp * 64 + slot * 8]);
    }
    #pragma unroll
    for (int ni = 0; ni < 8; ++ni) {
      int rb = wc * 128 + ni * 16 + l15;
      int rp = rb >> 1;
      int slot = (((rb & 1) << 2) | lhi) ^ (rp & 7);
      s16x8 bf = *(const s16x8*)(&lB[cur][rp * 64 + slot * 8]);
      #pragma unroll
      for (int mi = 0; mi < 2; ++mi)
        acc[mi][ni] = __builtin_amdgcn_mfma_f32_16x16x32_bf16(af[mi], bf, acc[mi][ni], 0, 0, 0);
    }
    __syncthreads();  // drains this kt's prefetch; releases cur for restage
    cur ^= 1;
  }

  // epilogue: + colconst, plain dword scatter stores (proven best shape)
  int grow0 = brow * 128 + wr * 32;
  int gcol0 = bcol * 256 + wc * 128;
  float cc[8];
  #pragma unroll
  for (int ni = 0; ni < 8; ++ni) cc[ni] = colconst[gcol0 + ni * 16 + l15];
  #pragma unroll
  for (int mi = 0; mi < 2; ++mi) {
    #pragma unroll
    for (int r = 0; r < 4; ++r) {
      size_t rbase = (size_t)(grow0 + mi * 16 + lhi * 4 + r) * LROW + 1;
      #pragma unroll
      for (int ni = 0; ni < 8; ++ni)
        out[rbase + gcol0 + ni * 16 + l15] = acc[mi][ni][r] + cc[ni];
    }
  }
}

extern "C" void kernel_launch(void* const* d_in, const int* in_sizes, int n_in,
                              void* d_out, int out_size, void* d_ws, size_t ws_size,
                              hipStream_t stream) {
  const float* inputs          = (const float*)d_in[0];
  const int*   labels          = (const int*)d_in[1];
  const int*   sample_ids      = (const int*)d_in[2];
  const float* true_log_freq   = (const float*)d_in[3];
  const float* sample_log_freq = (const float*)d_in[4];
  const float* weight          = (const float*)d_in[5];
  const float* bias            = (const float*)d_in[6];
  float* out = (float*)d_out;

  u16* wsA = (u16*)d_ws;                                      // 4 MB
  u16* wsB = wsA + (size_t)BATCH * NHID;                      // 4 MB
  float* colconst = (float*)(wsB + (size_t)NSAMPLED * NHID);  // 32 KB

  hipLaunchKernelGGL(k_prep, dim3(4096), dim3(256), 0, stream,
                     inputs, labels, sample_ids, true_log_freq, sample_log_freq,
                     weight, bias, wsA, wsB, colconst, out);
  hipLaunchKernelGGL(k_gemm, dim3(2048), dim3(512), 0, stream, wsA, wsB, colconst, out);
}